// Round 1
// 121.424 us; speedup vs baseline: 1.1823x; 1.1823x over previous
//
#include <hip/hip_runtime.h>
#include <hip/hip_bf16.h>

// Problem constants (fixed by reference setup: N=4096, D=512, C=100)
#define D_DIM 512
#define KSTEPS 16          // 512 / 32 (K per MFMA)
#define BM 64              // row-indices per block (shared by p2i AND i2i)
#define BN 64              // columns per LDS tile
#define GRIDY 8            // column chunks across grid -> 64*8 = 512 blocks = 2/CU

typedef __bf16 bf16x8 __attribute__((ext_vector_type(8)));
typedef float  f32x4  __attribute__((ext_vector_type(4)));

__device__ __forceinline__ unsigned short f2bf_rne(float x) {
    unsigned int u = __float_as_uint(x);
    u += 0x7FFFu + ((u >> 16) & 1u);
    return (unsigned short)(u >> 16);
}

// async global->LDS, 16B per lane. Dest is wave-uniform base + lane*16 (HW rule).
__device__ __forceinline__ void g2l16(const void* g, void* l) {
    __builtin_amdgcn_global_load_lds(
        (const __attribute__((address_space(1))) unsigned int*)g,
        (__attribute__((address_space(3))) unsigned int*)l, 16, 0, 0);
}

// rows [0,N): inst_embed -> instb ; rows [N,2N): proxy -> proxyb
__global__ __launch_bounds__(128) void normalize_rows(
    const float* __restrict__ inst, const float* __restrict__ proxy,
    unsigned short* __restrict__ instb, unsigned short* __restrict__ proxyb, int N)
{
    int row = blockIdx.x;
    const float* src;
    unsigned short* dst;
    if (row < N) { src = inst  + (size_t)row * D_DIM;        dst = instb  + (size_t)row * D_DIM; }
    else         { src = proxy + (size_t)(row - N) * D_DIM;  dst = proxyb + (size_t)(row - N) * D_DIM; }
    int t = threadIdx.x;                       // 128 threads x float4 = 512 elems
    float4 v = ((const float4*)src)[t];
    float ss = v.x*v.x + v.y*v.y + v.z*v.z + v.w*v.w;
    #pragma unroll
    for (int off = 32; off > 0; off >>= 1) ss += __shfl_down(ss, off, 64);
    __shared__ float wss[2];
    if ((t & 63) == 0) wss[t >> 6] = ss;
    __syncthreads();
    float inv = 1.0f / fmaxf(sqrtf(wss[0] + wss[1]), 1e-8f);
    ushort4 o;
    o.x = f2bf_rne(v.x * inv); o.y = f2bf_rne(v.y * inv);
    o.z = f2bf_rne(v.z * inv); o.w = f2bf_rne(v.w * inv);
    ((ushort4*)dst)[t] = o;
}

// Fused: per block, 64 row-indices; BOTH similarity matrices computed against the
// same staged B tile (B is always normalized inst). Each B fragment read from LDS
// feeds TWO MFMAs (proxy-A and inst-A) -> halves LDS bytes per FLOP.
// nd layout: [p2i_num | p2i_den | i2i_num | i2i_den], each N floats, pre-zeroed.
__global__ __launch_bounds__(256, 2) void fused_scores(
    const unsigned short* __restrict__ instb,
    const unsigned short* __restrict__ proxyb,
    const float* __restrict__ negmask,   // [C, N]
    const int*  __restrict__ labels,     // [N]
    const float* __restrict__ temp_p,
    const float* __restrict__ margin_p,
    float* __restrict__ nd,
    int N, int colsPerBlock)
{
    __shared__ unsigned short Bt[BN * D_DIM];   // 64 KB, xor-swizzled 16B chunks

    const int tid  = threadIdx.x;
    const int lane = tid & 63;
    const int wave = tid >> 6;      // 0..3
    const int quad = lane >> 4;     // 0..3
    const int l16  = lane & 15;

    const int row0 = blockIdx.x * BM + wave * 16;   // wave's 16 row-indices

    const float temp  = *temp_p;
    const float scale = 1.44269504088896340736f / temp;   // log2(e)/t
    const float bias  = -(*margin_p) * scale;

    // Two A slabs resident in registers: MFMA A-layout A[m=lane&15][k=quad*8+j]
    bf16x8 Ap[KSTEPS], Ai[KSTEPS];
    {
        const unsigned short* pr = proxyb + (size_t)(row0 + l16) * D_DIM + quad * 8;
        const unsigned short* ir = instb  + (size_t)(row0 + l16) * D_DIM + quad * 8;
        #pragma unroll
        for (int ks = 0; ks < KSTEPS; ks++) {
            Ap[ks] = *(const bf16x8*)(pr + ks * 32);
            Ai[ks] = *(const bf16x8*)(ir + ks * 32);
        }
    }

    // labels for this lane's 4 output rows (C/D layout: row = quad*4 + reg);
    // identical for p2i and i2i (same row index)
    int lab[4];
    #pragma unroll
    for (int r = 0; r < 4; r++) lab[r] = labels[row0 + quad * 4 + r];

    float numP[4] = {0.f,0.f,0.f,0.f}, denP[4] = {0.f,0.f,0.f,0.f};
    float numI[4] = {0.f,0.f,0.f,0.f}, denI[4] = {0.f,0.f,0.f,0.f};

    const int j0base = blockIdx.y * colsPerBlock;
    for (int jt = 0; jt < colsPerBlock; jt += BN) {
        const int j0 = j0base + jt;
        __syncthreads();   // protect previous tile's reads before overwrite
        // Stage B tile: 64 rows x 512 bf16 via global_load_lds (16B/lane).
        // LDS dest is linear; the xor-swizzle is applied to the SOURCE chunk,
        // matching the swizzled read below (rule: both-sides involution).
        #pragma unroll
        for (int it = 0; it < (BN * (D_DIM / 8)) / 256; it++) {
            const int br = it * 4 + wave;                // row in tile (wave-uniform)
            const unsigned short* src =
                instb + (size_t)(j0 + br) * D_DIM + ((lane ^ (br & 7)) * 8);
            g2l16(src, &Bt[(size_t)(it * 256 + wave * 64) * 8]);
        }
        __syncthreads();   // vmcnt(0) drain + barrier: tile ready

        f32x4 accP[4] = {}, accI[4] = {};   // 4 column groups of 16, x2 matrices
        #pragma unroll
        for (int ks = 0; ks < KSTEPS; ks++) {
            #pragma unroll
            for (int cg = 0; cg < 4; cg++) {
                const int rB  = cg * 16 + l16;               // B column = LDS row
                const int chs = (ks * 4 + quad) ^ (rB & 7);
                bf16x8 b = *(const bf16x8*)&Bt[(size_t)rB * D_DIM + chs * 8];
                accP[cg] = __builtin_amdgcn_mfma_f32_16x16x32_bf16(Ap[ks], b, accP[cg], 0, 0, 0);
                accI[cg] = __builtin_amdgcn_mfma_f32_16x16x32_bf16(Ai[ks], b, accI[cg], 0, 0, 0);
            }
        }

        // Epilogue: zone = exp2(sim*scale + bias); one mask load feeds both matrices
        #pragma unroll
        for (int cg = 0; cg < 4; cg++) {
            const int j = j0 + cg * 16 + l16;
            #pragma unroll
            for (int r = 0; r < 4; r++) {
                const float m = negmask[(size_t)lab[r] * N + j];
                float zp = exp2f(accP[cg][r] * scale + bias);
                float zi = exp2f(accI[cg][r] * scale + bias);
                denP[r] += zp; numP[r] += zp * m;
                denI[r] += zi; numI[r] += zi * m;
            }
        }
    }

    // Reduce across the 16 lanes (l16) sharing each output row, then atomicAdd
    #pragma unroll
    for (int r = 0; r < 4; r++) {
        float np = numP[r], dp = denP[r], ni = numI[r], di = denI[r];
        #pragma unroll
        for (int off = 8; off > 0; off >>= 1) {
            np += __shfl_down(np, off, 16);
            dp += __shfl_down(dp, off, 16);
            ni += __shfl_down(ni, off, 16);
            di += __shfl_down(di, off, 16);
        }
        if (l16 == 0) {
            const int row = row0 + quad * 4 + r;
            atomicAdd(&nd[row],         np);
            atomicAdd(&nd[N + row],     dp);
            atomicAdd(&nd[2 * N + row], ni);
            atomicAdd(&nd[3 * N + row], di);
        }
    }
}

__global__ __launch_bounds__(1024) void loss_reduce(
    const float* __restrict__ nd, const float* __restrict__ temp_p,
    float* __restrict__ out, int N)
{
    const float t = *temp_p;
    float s = 0.f;
    for (int i = threadIdx.x; i < N; i += 1024) {
        // -log(t*n/d) = log d - log n - log t ; the -log t terms are folded at the end
        s += (logf(nd[N + i])     - logf(nd[i]));           // p2i
        s += (logf(nd[3 * N + i]) - logf(nd[2 * N + i]));   // i2i
    }
    #pragma unroll
    for (int off = 32; off > 0; off >>= 1) s += __shfl_down(s, off, 64);
    __shared__ float wss[16];
    if ((threadIdx.x & 63) == 0) wss[threadIdx.x >> 6] = s;
    __syncthreads();
    if (threadIdx.x < 16) {
        float v = wss[threadIdx.x];
        #pragma unroll
        for (int off = 8; off > 0; off >>= 1) v += __shfl_down(v, off, 16);
        if (threadIdx.x == 0) out[0] = v / (float)N - 2.0f * logf(t);
    }
}

extern "C" void kernel_launch(void* const* d_in, const int* in_sizes, int n_in,
                              void* d_out, int out_size, void* d_ws, size_t ws_size,
                              hipStream_t stream)
{
    const float* inst     = (const float*)d_in[0];
    const float* proxy    = (const float*)d_in[1];
    const float* negmask  = (const float*)d_in[2];
    const int*   labels   = (const int*)d_in[3];
    const float* temp_p   = (const float*)d_in[4];
    const float* margin_p = (const float*)d_in[5];
    float* out = (float*)d_out;

    const int N = in_sizes[3];    // 4096 (D fixed at 512 per reference)

    unsigned short* instb  = (unsigned short*)d_ws;
    unsigned short* proxyb = instb + (size_t)N * D_DIM;
    float* nd = (float*)(proxyb + (size_t)N * D_DIM);

    hipMemsetAsync(nd, 0, sizeof(float) * 4 * N, stream);
    normalize_rows<<<2 * N, 128, 0, stream>>>(inst, proxy, instb, proxyb, N);
    dim3 grid(N / BM, GRIDY);
    fused_scores<<<grid, 256, 0, stream>>>(instb, proxyb, negmask, labels,
                                           temp_p, margin_p, nd, N, N / GRIDY);
    loss_reduce<<<1, 1024, 0, stream>>>(nd, temp_p, out, N);
}

// Round 2
// 119.918 us; speedup vs baseline: 1.1972x; 1.0126x over previous
//
#include <hip/hip_runtime.h>
#include <hip/hip_bf16.h>

// Problem constants (fixed by reference setup: N=4096, D=512, C=100)
#define D_DIM 512
#define KSTEPS 16          // 512 / 32 (K per MFMA)
#define BM 64              // row-indices per block (shared by p2i AND i2i)
#define BN 32              // columns per LDS tile (half-size, double-buffered)
#define GRIDY 8            // column chunks across grid -> 64*8 = 512 blocks = 2/CU

typedef __bf16 bf16x8 __attribute__((ext_vector_type(8)));
typedef float  f32x4  __attribute__((ext_vector_type(4)));

__device__ __forceinline__ unsigned short f2bf_rne(float x) {
    unsigned int u = __float_as_uint(x);
    u += 0x7FFFu + ((u >> 16) & 1u);
    return (unsigned short)(u >> 16);
}

// async global->LDS, 16B per lane. Dest is wave-uniform base + lane*16 (HW rule).
__device__ __forceinline__ void g2l16(const void* g, void* l) {
    __builtin_amdgcn_global_load_lds(
        (const __attribute__((address_space(1))) unsigned int*)g,
        (__attribute__((address_space(3))) unsigned int*)l, 16, 0, 0);
}

// 512 blocks x 256 threads; each wave normalizes 4 rows (lane-parallel over D).
// rows [0,N): inst_embed -> instb ; rows [N,2N): proxy -> proxyb.
// Also zeroes the nd accumulator (blocks 0..15), replacing the memset dispatch.
__global__ __launch_bounds__(256) void normalize_rows(
    const float* __restrict__ inst, const float* __restrict__ proxy,
    unsigned short* __restrict__ instb, unsigned short* __restrict__ proxyb,
    float* __restrict__ nd, int N)
{
    const int lane = threadIdx.x & 63;
    const int wave = threadIdx.x >> 6;
    const int base = blockIdx.x * 16 + wave * 4;
    #pragma unroll
    for (int i = 0; i < 4; ++i) {
        const int row = base + i;
        const float* src;
        unsigned short* dst;
        if (row < N) { src = inst  + (size_t)row * D_DIM;        dst = instb  + (size_t)row * D_DIM; }
        else         { src = proxy + (size_t)(row - N) * D_DIM;  dst = proxyb + (size_t)(row - N) * D_DIM; }
        float4 v0 = ((const float4*)src)[lane * 2];
        float4 v1 = ((const float4*)src)[lane * 2 + 1];
        float ss = v0.x*v0.x + v0.y*v0.y + v0.z*v0.z + v0.w*v0.w
                 + v1.x*v1.x + v1.y*v1.y + v1.z*v1.z + v1.w*v1.w;
        #pragma unroll
        for (int off = 32; off > 0; off >>= 1) ss += __shfl_xor(ss, off, 64);
        const float inv = 1.0f / fmaxf(sqrtf(ss), 1e-8f);
        ushort4 o0, o1;
        o0.x = f2bf_rne(v0.x * inv); o0.y = f2bf_rne(v0.y * inv);
        o0.z = f2bf_rne(v0.z * inv); o0.w = f2bf_rne(v0.w * inv);
        o1.x = f2bf_rne(v1.x * inv); o1.y = f2bf_rne(v1.y * inv);
        o1.z = f2bf_rne(v1.z * inv); o1.w = f2bf_rne(v1.w * inv);
        ((ushort4*)dst)[lane * 2]     = o0;
        ((ushort4*)dst)[lane * 2 + 1] = o1;
    }
    if (blockIdx.x < 16)   // 16 blocks x 256 threads x 16B = 16384 floats
        ((float4*)nd)[blockIdx.x * 256 + threadIdx.x] = make_float4(0.f, 0.f, 0.f, 0.f);
}

// Fused: per block, 64 row-indices; BOTH similarity matrices computed against the
// same staged B tile. 2-phase software pipeline: stage(next tile, async g2l) is
// issued BEFORE compute(current tile); the single __syncthreads per tile then
// drains vmcnt at ~zero cost. Static Bt0/Bt1 + unroll-by-2 keeps alias analysis
// from inserting spurious vmcnt waits between g2l(other buf) and ds_read(cur buf).
// nd layout: [p2i_num | p2i_den | i2i_num | i2i_den], each N floats, pre-zeroed.
__global__ __launch_bounds__(256, 2) void fused_scores(
    const unsigned short* __restrict__ instb,
    const unsigned short* __restrict__ proxyb,
    const float* __restrict__ negmask,   // [C, N]
    const int*  __restrict__ labels,     // [N]
    const float* __restrict__ temp_p,
    const float* __restrict__ margin_p,
    float* __restrict__ nd,
    int N, int colsPerBlock)
{
    __shared__ unsigned short Bt0[BN * D_DIM];   // 32 KB
    __shared__ unsigned short Bt1[BN * D_DIM];   // 32 KB

    const int tid  = threadIdx.x;
    const int lane = tid & 63;
    const int wave = tid >> 6;      // 0..3
    const int quad = lane >> 4;     // 0..3
    const int l16  = lane & 15;

    const int row0 = blockIdx.x * BM + wave * 16;   // wave's 16 row-indices

    const float temp  = *temp_p;
    const float scale = 1.44269504088896340736f / temp;   // log2(e)/t
    const float bias  = -(*margin_p) * scale;

    // Two A slabs resident in registers: MFMA A-layout A[m=lane&15][k=quad*8+j]
    bf16x8 Ap[KSTEPS], Ai[KSTEPS];
    {
        const unsigned short* pr = proxyb + (size_t)(row0 + l16) * D_DIM + quad * 8;
        const unsigned short* ir = instb  + (size_t)(row0 + l16) * D_DIM + quad * 8;
        #pragma unroll
        for (int ks = 0; ks < KSTEPS; ks++) {
            Ap[ks] = *(const bf16x8*)(pr + ks * 32);
            Ai[ks] = *(const bf16x8*)(ir + ks * 32);
        }
    }

    // labels for this lane's 4 output rows (C/D layout: row = quad*4 + reg)
    int lab[4];
    #pragma unroll
    for (int r = 0; r < 4; r++) lab[r] = labels[row0 + quad * 4 + r];

    float numP[4] = {0.f,0.f,0.f,0.f}, denP[4] = {0.f,0.f,0.f,0.f};
    float numI[4] = {0.f,0.f,0.f,0.f}, denI[4] = {0.f,0.f,0.f,0.f};

    const int j0base = blockIdx.y * colsPerBlock;
    const int nt     = colsPerBlock / BN;           // 16 (even)

    // Stage tile t (BN rows x 512 bf16) into B. LDS dest linear per row;
    // xor-swizzle applied to the SOURCE 16B-chunk index (both-sides involution).
    auto stage = [&](unsigned short (&B)[BN * D_DIM], int t) {
        const int j0 = j0base + t * BN;
        #pragma unroll
        for (int it = 0; it < BN / 4; ++it) {       // 8 rounds, 1 row per wave
            const int br = it * 4 + wave;           // row in tile (wave-uniform)
            const unsigned short* src =
                instb + (size_t)(j0 + br) * D_DIM + ((lane ^ (br & 7)) * 8);
            g2l16(src, &B[br * D_DIM]);
        }
    };

    auto compute = [&](unsigned short (&B)[BN * D_DIM], int t) {
        const int j0 = j0base + t * BN;
        f32x4 accP[2] = {}, accI[2] = {};
        #pragma unroll
        for (int ks = 0; ks < KSTEPS; ++ks) {
            #pragma unroll
            for (int cg = 0; cg < 2; ++cg) {
                const int rB  = cg * 16 + l16;               // B column = LDS row
                const int chs = (ks * 4 + quad) ^ (rB & 7);
                bf16x8 b = *(const bf16x8*)&B[(size_t)rB * D_DIM + chs * 8];
                accP[cg] = __builtin_amdgcn_mfma_f32_16x16x32_bf16(Ap[ks], b, accP[cg], 0, 0, 0);
                accI[cg] = __builtin_amdgcn_mfma_f32_16x16x32_bf16(Ai[ks], b, accI[cg], 0, 0, 0);
            }
        }
        // Epilogue: zone = exp2(sim*scale + bias); one mask load feeds both matrices
        #pragma unroll
        for (int cg = 0; cg < 2; ++cg) {
            const int j = j0 + cg * 16 + l16;
            #pragma unroll
            for (int r = 0; r < 4; ++r) {
                const float m = negmask[(size_t)lab[r] * N + j];
                float zp = exp2f(accP[cg][r] * scale + bias);
                float zi = exp2f(accI[cg][r] * scale + bias);
                denP[r] += zp; numP[r] += zp * m;
                denI[r] += zi; numI[r] += zi * m;
            }
        }
    };

    stage(Bt0, 0);
    __syncthreads();                     // drains vmcnt: tile 0 ready
    for (int t = 0; t < nt; t += 2) {
        stage(Bt1, t + 1);               // async: lands during compute below
        compute(Bt0, t);
        __syncthreads();                 // tile t+1 ready; Bt0 free
        if (t + 2 < nt) stage(Bt0, t + 2);
        compute(Bt1, t + 1);
        __syncthreads();                 // tile t+2 ready; Bt1 free
    }

    // Reduce across the 16 lanes (l16) sharing each output row, then atomicAdd
    #pragma unroll
    for (int r = 0; r < 4; r++) {
        float np = numP[r], dp = denP[r], ni = numI[r], di = denI[r];
        #pragma unroll
        for (int off = 8; off > 0; off >>= 1) {
            np += __shfl_down(np, off, 16);
            dp += __shfl_down(dp, off, 16);
            ni += __shfl_down(ni, off, 16);
            di += __shfl_down(di, off, 16);
        }
        if (l16 == 0) {
            const int row = row0 + quad * 4 + r;
            atomicAdd(&nd[row],         np);
            atomicAdd(&nd[N + row],     dp);
            atomicAdd(&nd[2 * N + row], ni);
            atomicAdd(&nd[3 * N + row], di);
        }
    }
}

__global__ __launch_bounds__(1024) void loss_reduce(
    const float* __restrict__ nd, const float* __restrict__ temp_p,
    float* __restrict__ out, int N)
{
    const float t = *temp_p;
    float s = 0.f;
    for (int i = threadIdx.x; i < N; i += 1024) {
        s += (logf(nd[N + i])     - logf(nd[i]));           // p2i
        s += (logf(nd[3 * N + i]) - logf(nd[2 * N + i]));   // i2i
    }
    #pragma unroll
    for (int off = 32; off > 0; off >>= 1) s += __shfl_down(s, off, 64);
    __shared__ float wss[16];
    if ((threadIdx.x & 63) == 0) wss[threadIdx.x >> 6] = s;
    __syncthreads();
    if (threadIdx.x < 16) {
        float v = wss[threadIdx.x];
        #pragma unroll
        for (int off = 8; off > 0; off >>= 1) v += __shfl_down(v, off, 16);
        if (threadIdx.x == 0) out[0] = v / (float)N - 2.0f * logf(t);
    }
}

extern "C" void kernel_launch(void* const* d_in, const int* in_sizes, int n_in,
                              void* d_out, int out_size, void* d_ws, size_t ws_size,
                              hipStream_t stream)
{
    const float* inst     = (const float*)d_in[0];
    const float* proxy    = (const float*)d_in[1];
    const float* negmask  = (const float*)d_in[2];
    const int*   labels   = (const int*)d_in[3];
    const float* temp_p   = (const float*)d_in[4];
    const float* margin_p = (const float*)d_in[5];
    float* out = (float*)d_out;

    const int N = in_sizes[3];    // 4096 (D fixed at 512 per reference)

    unsigned short* instb  = (unsigned short*)d_ws;
    unsigned short* proxyb = instb + (size_t)N * D_DIM;
    float* nd = (float*)(proxyb + (size_t)N * D_DIM);

    normalize_rows<<<2 * N / 16, 256, 0, stream>>>(inst, proxy, instb, proxyb, nd, N);
    dim3 grid(N / BM, GRIDY);
    fused_scores<<<grid, 256, 0, stream>>>(instb, proxyb, negmask, labels,
                                           temp_p, margin_p, nd, N, N / GRIDY);
    loss_reduce<<<1, 1024, 0, stream>>>(nd, temp_p, out, N);
}